// Round 9
// baseline (158.461 us; speedup 1.0000x reference)
//
#include <hip/hip_runtime.h>
#include <math.h>

#define N_PTS   65536
#define N_CTR   1024       // per set
#define NCELLS  256        // 16x16 Morton cells
#define NSLICE  64         // 64 slices x 1024 sorted points
#define CHUNK   256        // centers per chunk -> 4 chunks per set
#define MAXL    (CHUNK + 4)
#define CUT     44.0f      // cull threshold (log2 units)
#define LOG2E   1.4426950408889634f

#if __has_builtin(__builtin_amdgcn_exp2f)
#define EXP2(v) __builtin_amdgcn_exp2f(v)
#else
#define EXP2(v) exp2f(v)
#endif

__device__ __forceinline__ int morton4(int v) {   // spread 4 bits to even positions
    v = (v | (v << 2)) & 0x33;
    v = (v | (v << 1)) & 0x55;
    return v;
}
__device__ __forceinline__ int cell_of(float2 p) {
    int cx = (int)(p.x * 16.f); cx = cx > 15 ? 15 : (cx < 0 ? 0 : cx);
    int cy = (int)(p.y * 16.f); cy = cy > 15 ? 15 : (cy < 0 ? 0 : cy);
    return morton4(cx) | (morton4(cy) << 1);
}

// K1: fold constants, zero outputs, count points per Morton cell.
__global__ __launch_bounds__(256) void prep_kernel(
    const float* __restrict__ x,
    const float* __restrict__ h0, const float* __restrict__ c0, const float* __restrict__ w0,
    const float* __restrict__ h1, const float* __restrict__ c1, const float* __restrict__ w1,
    const float* __restrict__ h2, const float* __restrict__ c2, const float* __restrict__ w2,
    float4* __restrict__ RA, float4* __restrict__ RB, float* __restrict__ RC,
    float4* __restrict__ RT, unsigned int* __restrict__ cnt,
    float2* __restrict__ out2)
{
    const int idx = blockIdx.x * 256 + threadIdx.x;   // 0..65535

    { // zero outputs: 393216 floats = 3 x 65536 float2
        float2 z = make_float2(0.f, 0.f);
        out2[idx] = z; out2[idx + 65536] = z; out2[idx + 131072] = z;
    }
    { // bucket count (cnt pre-zeroed by memsetAsync)
        float2 p = ((const float2*)x)[idx];
        atomicAdd(&cnt[cell_of(p)], 1u);
    }
    if (idx >= 3 * N_CTR) return;

    const int set = idx >> 10;
    const int j   = idx & (N_CTR - 1);
    const float*  h = (set == 0) ? h0 : ((set == 1) ? h1 : h2);
    const float2* c = (const float2*)((set == 0) ? c0 : ((set == 1) ? c1 : c2));
    const float2* w = (const float2*)((set == 0) ? w0 : ((set == 1) ? w1 : w2));

    float2 cj = c[j];
    float2 wj = w[j];
    float  hh = h[j];
    float d1 = wj.x * wj.x;
    float d2 = wj.y * wj.y;
    float zb =  2.f * cj.x * d1 * LOG2E;
    float zc = -d1 * LOG2E;
    float zd =  2.f * cj.y * d2 * LOG2E;
    float ze = -d2 * LOG2E;
    float za = -(cj.x * cj.x * d1 + cj.y * cj.y * d2) * LOG2E;
    float k0, k1, k2, k3;
    if (set == 0) {
        k0 = -2.f * hh * d1;  k1 = 2.f * hh * d1 * cj.x;
        k2 = -2.f * hh * d2;  k3 = 2.f * hh * d2 * cj.y;
    } else if (set == 1) {
        k0 = hh;  k1 = -2.f * hh * d1;  k2 = 2.f * hh * d1 * cj.x;  k3 = 0.f;
    } else {
        k0 = hh;  k1 = -2.f * hh * d2;  k2 = 2.f * hh * d2 * cj.y;  k3 = 0.f;
    }
    RA[idx] = make_float4(zb, zc, zd, ze);
    RB[idx] = make_float4(za, k0, k1, k2);
    RC[idx] = k3;
    RT[idx] = make_float4(cj.x, cj.y, d1 * LOG2E, d2 * LOG2E);
}

// K2: exclusive prefix sum over 256 cells (1 block).
__global__ __launch_bounds__(256) void prefix_kernel(
    const unsigned int* __restrict__ cnt, unsigned int* __restrict__ cursor)
{
    __shared__ unsigned int s[256];
    const int t = threadIdx.x;
    unsigned int v = cnt[t];
    s[t] = v;
    __syncthreads();
    unsigned int acc = v;
    for (int off = 1; off < 256; off <<= 1) {
        unsigned int y = (t >= off) ? s[t - off] : 0u;
        __syncthreads();
        acc += y; s[t] = acc;
        __syncthreads();
    }
    cursor[t] = acc - v;   // exclusive
}

// K3: scatter point indices into cell-sorted order.
__global__ __launch_bounds__(256) void scatter_kernel(
    const float* __restrict__ x, unsigned int* __restrict__ cursor,
    unsigned short* __restrict__ sortedIdx)
{
    const int i = blockIdx.x * 256 + threadIdx.x;
    float2 p = ((const float2*)x)[i];
    unsigned int slot = atomicAdd(&cursor[cell_of(p)], 1u);
    sortedIdx[slot] = (unsigned short)i;
}

// K4: main. Block = (slice of 1024 sorted points) x set x chunk-of-256-centers.
__global__ __launch_bounds__(256) void srbf_main(
    const float* __restrict__ x,
    const float4* __restrict__ RA, const float4* __restrict__ RB,
    const float*  __restrict__ RC, const float4* __restrict__ RT,
    const unsigned short* __restrict__ sortedIdx,
    float* __restrict__ out)
{
    __shared__ float4 sA[MAXL];
    __shared__ float4 sB[MAXL];
    __shared__ float  sC[MAXL];
    __shared__ int    wtot[4];
    __shared__ float4 bbx[4];

    const int bid   = blockIdx.x;        // 0..767
    const int slice = bid / 12;          // same-slice blocks adjacent (L2 reuse)
    const int rr    = bid % 12;
    const int set   = rr >> 2;
    const int chunk = rr & 3;
    const int tid   = threadIdx.x;
    const int lane  = tid & 63;
    const int wv    = tid >> 6;
    const int cbase = set * N_CTR + chunk * CHUNK;

    // ---- load this thread's 4 points (sorted order; exact, no masks) ----
    const float2* xp = (const float2*)x;
    const int sbase = slice * 1024 + tid;
    int   O[4];
    float X[4], Y[4];
    #pragma unroll
    for (int k = 0; k < 4; ++k) {
        int o = sortedIdx[sbase + 256 * k];
        O[k] = o;
        float2 p = xp[o];
        X[k] = p.x; Y[k] = p.y;
    }

    // ---- block bbox (wave shuffle reduce, then cross-wave via LDS) ----
    float mnx = fminf(fminf(X[0], X[1]), fminf(X[2], X[3]));
    float mxx = fmaxf(fmaxf(X[0], X[1]), fmaxf(X[2], X[3]));
    float mny = fminf(fminf(Y[0], Y[1]), fminf(Y[2], Y[3]));
    float mxy = fmaxf(fmaxf(Y[0], Y[1]), fmaxf(Y[2], Y[3]));
    #pragma unroll
    for (int d = 1; d < 64; d <<= 1) {
        mnx = fminf(mnx, __shfl_xor(mnx, d));
        mxx = fmaxf(mxx, __shfl_xor(mxx, d));
        mny = fminf(mny, __shfl_xor(mny, d));
        mxy = fmaxf(mxy, __shfl_xor(mxy, d));
    }
    if (lane == 0) bbx[wv] = make_float4(mnx, mxx, mny, mxy);
    __syncthreads();
    {
        float4 b0 = bbx[0], b1 = bbx[1], b2 = bbx[2], b3 = bbx[3];
        mnx = fminf(fminf(b0.x, b1.x), fminf(b2.x, b3.x));
        mxx = fmaxf(fmaxf(b0.y, b1.y), fmaxf(b2.y, b3.y));
        mny = fminf(fminf(b0.z, b1.z), fminf(b2.z, b3.z));
        mxy = fmaxf(fmaxf(b0.w, b1.w), fmaxf(b2.w, b3.w));
    }

    // ---- cull 256 centers against bbox; wave-scan compaction into LDS ----
    const int jg = cbase + tid;
    float4 T = RT[jg];
    float dxm = fmaxf(fmaxf(mnx - T.x, T.x - mxx), 0.f);
    float dym = fmaxf(fmaxf(mny - T.y, T.y - mxy), 0.f);
    float q   = dxm * dxm * T.z + dym * dym * T.w;
    const bool live = q < CUT;
    unsigned long long mask = __ballot(live);
    if (lane == 0) wtot[wv] = __popcll(mask);
    __syncthreads();
    int base = 0, m = 0;
    #pragma unroll
    for (int w2 = 0; w2 < 4; ++w2) {
        int t = wtot[w2];
        m += t;
        if (w2 < wv) base += t;
    }
    if (live) {
        int p = base + __popcll(mask & ((1ull << lane) - 1ull));
        sA[p] = RA[jg]; sB[p] = RB[jg]; sC[p] = RC[jg];
    }
    const int mPad = (m + 3) & ~3;
    if (tid < mPad - m) {   // zero-pad: s=0 -> e=1, k=0 -> contributes 0
        sA[m + tid] = make_float4(0.f, 0.f, 0.f, 0.f);
        sB[m + tid] = make_float4(0.f, 0.f, 0.f, 0.f);
        sC[m + tid] = 0.f;
    }
    __syncthreads();

    // ---- main loop: 4 pts x (4 poly FMA + exp2 + 4 acc FMA), unroll 4 ----
    float A0[4], A1[4], A2[4], A3[4];
    #pragma unroll
    for (int k = 0; k < 4; ++k) { A0[k] = A1[k] = A2[k] = A3[k] = 0.f; }

    for (int t = 0; t < mPad; t += 4) {
        #pragma unroll
        for (int u = 0; u < 4; ++u) {
            const float4 A  = sA[t + u];
            const float4 K  = sB[t + u];
            const float  k3 = sC[t + u];
            #pragma unroll
            for (int k = 0; k < 4; ++k) {
                float u1 = fmaf(X[k], A.y, A.x);
                float u2 = fmaf(X[k], u1,  K.x);
                float u3 = fmaf(Y[k], A.w, A.z);
                float s  = fmaf(Y[k], u3,  u2);
                float e  = EXP2(s);
                A0[k] = fmaf(K.y, e, A0[k]);
                A1[k] = fmaf(K.z, e, A1[k]);
                A2[k] = fmaf(K.w, e, A2[k]);
                A3[k] = fmaf(k3,  e, A3[k]);
            }
        }
    }

    // ---- epilogue: per-set combine, atomic accumulate (4 chunks/set) ----
    float* ob = out + (size_t)set * 2 * N_PTS;
    #pragma unroll
    for (int k = 0; k < 4; ++k) {
        float r1, r2;
        if (set == 0)      { r1 = fmaf(X[k], A0[k], A1[k]); r2 = fmaf(Y[k], A2[k], A3[k]); }
        else if (set == 1) { r1 = A0[k];                    r2 = fmaf(X[k], A1[k], A2[k]); }
        else               { r1 = A0[k];                    r2 = fmaf(Y[k], A1[k], A2[k]); }
        atomicAdd(&ob[O[k]],         r1);
        atomicAdd(&ob[N_PTS + O[k]], r2);
    }
}

extern "C" void kernel_launch(void* const* d_in, const int* in_sizes, int n_in,
                              void* d_out, int out_size, void* d_ws, size_t ws_size,
                              hipStream_t stream) {
    const float* x  = (const float*)d_in[0];
    const float* h1 = (const float*)d_in[1];
    const float* c1 = (const float*)d_in[2];
    const float* w1 = (const float*)d_in[3];
    const float* h2 = (const float*)d_in[4];
    const float* c2 = (const float*)d_in[5];
    const float* w2 = (const float*)d_in[6];
    const float* h3 = (const float*)d_in[7];
    const float* c3 = (const float*)d_in[8];
    const float* w3 = (const float*)d_in[9];

    char* ws = (char*)d_ws;
    float4* RA = (float4*)(ws);                            // 49152 B
    float4* RB = (float4*)(ws + 49152);                    // 49152 B
    float*  RC = (float*) (ws + 98304);                    // 12288 B
    float4* RT = (float4*)(ws + 110592);                   // 49152 B
    unsigned int*   cnt    = (unsigned int*)(ws + 159744); // 1024 B
    unsigned int*   cursor = (unsigned int*)(ws + 160768); // 1024 B
    unsigned short* sidx   = (unsigned short*)(ws + 161792); // 131072 B (total ~293 KB)

    hipMemsetAsync(cnt, 0, NCELLS * sizeof(unsigned int), stream);

    // K1: constants + zero out + per-cell counts
    prep_kernel<<<dim3(256), dim3(256), 0, stream>>>(
        x, h1, c1, w1, h2, c2, w2, h3, c3, w3, RA, RB, RC, RT, cnt, (float2*)d_out);

    // K2: prefix sum -> cursor
    prefix_kernel<<<dim3(1), dim3(256), 0, stream>>>(cnt, cursor);

    // K3: scatter to sorted order
    scatter_kernel<<<dim3(256), dim3(256), 0, stream>>>(x, cursor, sidx);

    // K4: 64 slices x 3 sets x 4 chunks = 768 blocks (3/CU exact)
    srbf_main<<<dim3(768), dim3(256), 0, stream>>>(
        x, RA, RB, RC, RT, sidx, (float*)d_out);
}